// Round 4
// baseline (683.846 us; speedup 1.0000x reference)
//
#include <hip/hip_runtime.h>

typedef __attribute__((ext_vector_type(8))) _Float16 f16x8;
typedef __attribute__((ext_vector_type(4))) _Float16 f16x4;
typedef __attribute__((ext_vector_type(4))) float f32x4;

#define LSTR 264   // halves; 528 B row stride, 16B-aligned for ds_read_b128
#define SS 4096
#define SD 256
#define SEG 128

__device__ __forceinline__ float fast_tanh(float x) {
    x = fminf(fmaxf(x, -15.f), 15.f);
    float ex = __expf(2.f * x);
    return (ex - 1.f) / (ex + 1.f);
}

// DIAGNOSTIC ROUND: identical per-rep work to R3, repeated `reps` (=4) times,
// idempotent outputs. dur_us delta vs R3 measures the true kernel time
// (harness reset traffic is the suspected dominant fixed cost).
extern "C" __global__ __launch_bounds__(512, 2)
void entity_tile_kernel(const float* __restrict__ hidden,
                        const float* __restrict__ mask,
                        const float* __restrict__ w,
                        const float* __restrict__ bias,
                        float* __restrict__ out,
                        int reps)
{
    extern __shared__ _Float16 smem[];
    _Float16* s_trsf = smem;                // 128 x LSTR (reused for attn)
    _Float16* s_seq  = smem + 128 * LSTR;   // 128 x LSTR

    const int bid  = blockIdx.x;            // b*32 + e
    const int b    = bid >> 5;
    const int e    = bid & 31;
    const int tid  = threadIdx.x;
    const int wv   = tid >> 6;               // 0..7
    const int lane = tid & 63;
    const int quad = lane >> 4;
    const int l15  = lane & 15;

    // opaque zero: defeats loop-invariant hoisting of global loads across reps
    const size_t opaq = (size_t)(reps >> 8);

    for (int rep = 0; rep < reps; ++rep) {
        const float* hid_p = hidden + opaq * (size_t)rep;
        const float* msk_p = mask   + opaq * (size_t)rep;
        const float* w_p   = w      + opaq * (size_t)rep;

        // ---------- phase 0: stage seq tile (128x256 f32 -> f16 LDS); write new_mask ----------
        {
            const float4* g4 = (const float4*)(hid_p + (size_t)bid * (SEG * SD));
            #pragma unroll
            for (int i = 0; i < 16; ++i) {
                int idx  = i * 512 + tid;        // float4 index; 64 per row
                int row  = idx >> 6;
                int col4 = (idx & 63) << 2;
                float4 v = g4[idx];
                f16x4 h = { (_Float16)v.x, (_Float16)v.y, (_Float16)v.z, (_Float16)v.w };
                *(f16x4*)&s_seq[row * LSTR + col4] = h;
            }
            float* nm = out + 65536 + (size_t)bid * 4096;
            #pragma unroll
            for (int i = 0; i < 2; ++i) {
                int idx = i * 512 + tid;         // float4 index within 4096
                float val = ((idx >> 5) == e) ? 1.0f : 0.0f;
                float4 q = {val, val, val, val};
                *(float4*)&nm[idx << 2] = q;
            }
        }

        // ---------- mask prefetch: wave owns score rows [wv*16, +16), C-layout ----------
        float mraw[8][4];
        {
            const int lw = wv * 16;
            const size_t mbase = (((size_t)b * SS) + (size_t)e * SEG) * SS + (size_t)e * SEG;
            #pragma unroll
            for (int r = 0; r < 4; ++r) {
                const int l = lw + quad * 4 + r;
                #pragma unroll
                for (int n = 0; n < 8; ++n)
                    mraw[n][r] = msk_p[mbase + (size_t)l * SS + n * 16 + l15];
            }
        }
        __syncthreads();

        // ---------- phase 1: trsf = tanh(seq @ w^T + b); wave owns out-cols [wv*32, +32) ----------
        {
            const int wn0 = wv * 32;
            f16x8 wb[2][8];
            float bv[2];
            #pragma unroll
            for (int nn = 0; nn < 2; ++nn) {
                const float* wrow = w_p + (size_t)(wn0 + nn * 16 + l15) * SD;
                bv[nn] = bias[wn0 + nn * 16 + l15];
                #pragma unroll
                for (int k = 0; k < 8; ++k) {
                    const float4* p = (const float4*)(wrow + k * 32 + quad * 8);
                    float4 u0 = p[0], u1 = p[1];
                    f16x8 v = { (_Float16)u0.x, (_Float16)u0.y, (_Float16)u0.z, (_Float16)u0.w,
                                (_Float16)u1.x, (_Float16)u1.y, (_Float16)u1.z, (_Float16)u1.w };
                    wb[nn][k] = v;
                }
            }
            const f32x4 fz = {0.f, 0.f, 0.f, 0.f};
            #pragma unroll
            for (int m2 = 0; m2 < 4; ++m2) {       // two 16-row tiles per iter -> 4 indep accs
                f32x4 acc[2][2] = {{fz, fz}, {fz, fz}};
                #pragma unroll
                for (int k = 0; k < 8; ++k) {
                    f16x8 a0 = *(const f16x8*)&s_seq[(m2 * 32 +      l15) * LSTR + k * 32 + quad * 8];
                    f16x8 a1 = *(const f16x8*)&s_seq[(m2 * 32 + 16 + l15) * LSTR + k * 32 + quad * 8];
                    #pragma unroll
                    for (int nn = 0; nn < 2; ++nn) {
                        acc[0][nn] = __builtin_amdgcn_mfma_f32_16x16x32_f16(a0, wb[nn][k], acc[0][nn], 0, 0, 0);
                        acc[1][nn] = __builtin_amdgcn_mfma_f32_16x16x32_f16(a1, wb[nn][k], acc[1][nn], 0, 0, 0);
                    }
                }
                #pragma unroll
                for (int h = 0; h < 2; ++h)
                    #pragma unroll
                    for (int nn = 0; nn < 2; ++nn)
                        #pragma unroll
                        for (int r = 0; r < 4; ++r)
                            s_trsf[(m2 * 32 + h * 16 + quad * 4 + r) * LSTR + wn0 + nn * 16 + l15] =
                                (_Float16)fast_tanh(acc[h][nn][r] + bv[nn]);
            }
        }
        __syncthreads();

        // ---------- phase 2: scores rows [wv*16,+16) = trsf @ seq^T; softmax; attn -> s_trsf ----------
        {
            const int lw = wv * 16;
            f16x8 at[8];
            #pragma unroll
            for (int k = 0; k < 8; ++k)
                at[k] = *(const f16x8*)&s_trsf[(lw + l15) * LSTR + k * 32 + quad * 8];

            const f32x4 fz = {0.f, 0.f, 0.f, 0.f};
            f32x4 sacc[8];
            #pragma unroll
            for (int n = 0; n < 8; ++n) sacc[n] = fz;

            #pragma unroll
            for (int k = 0; k < 8; ++k) {          // 8 independent accumulators per k step
                #pragma unroll
                for (int n = 0; n < 8; ++n) {
                    f16x8 bb = *(const f16x8*)&s_seq[(n * 16 + l15) * LSTR + k * 32 + quad * 8];
                    sacc[n] = __builtin_amdgcn_mfma_f32_16x16x32_f16(at[k], bb, sacc[n], 0, 0, 0);
                }
            }

            #pragma unroll
            for (int r = 0; r < 4; ++r) {
                const int l = lw + quad * 4 + r;
                float mx = -3.4e38f;
                #pragma unroll
                for (int n = 0; n < 8; ++n) {
                    float sv = sacc[n][r] + mraw[n][r];
                    sacc[n][r] = sv;
                    mx = fmaxf(mx, sv);
                }
                mx = fmaxf(mx, __shfl_xor(mx, 1, 64));
                mx = fmaxf(mx, __shfl_xor(mx, 2, 64));
                mx = fmaxf(mx, __shfl_xor(mx, 4, 64));
                mx = fmaxf(mx, __shfl_xor(mx, 8, 64));
                float sum = 0.f;
                #pragma unroll
                for (int n = 0; n < 8; ++n) {
                    float ev = __expf(sacc[n][r] - mx);
                    sacc[n][r] = ev;
                    sum += ev;
                }
                sum += __shfl_xor(sum, 1, 64);
                sum += __shfl_xor(sum, 2, 64);
                sum += __shfl_xor(sum, 4, 64);
                sum += __shfl_xor(sum, 8, 64);
                float inv = 1.f / sum;
                #pragma unroll
                for (int n = 0; n < 8; ++n)
                    s_trsf[(size_t)l * LSTR + n * 16 + l15] = (_Float16)(sacc[n][r] * inv);
            }
        }
        __syncthreads();

        // ---------- phase 3: ctx = attn @ seq; pooled = colmax; wave owns d-cols [wv*32,+32) ----------
        {
            f16x8 af[8][4];
            #pragma unroll
            for (int m = 0; m < 8; ++m)
                #pragma unroll
                for (int k = 0; k < 4; ++k)
                    af[m][k] = *(const f16x8*)&s_trsf[(m * 16 + l15) * LSTR + k * 32 + quad * 8];

            const int wn0 = wv * 32;
            const f32x4 fz = {0.f, 0.f, 0.f, 0.f};
            #pragma unroll
            for (int nn = 0; nn < 2; ++nn) {
                f16x8 bfr[4];
                #pragma unroll
                for (int k = 0; k < 4; ++k) {
                    f16x8 t;
                    #pragma unroll
                    for (int j = 0; j < 8; ++j)
                        t[j] = s_seq[(k * 32 + quad * 8 + j) * LSTR + wn0 + nn * 16 + l15];
                    bfr[k] = t;
                }
                f32x4 a[8];
                #pragma unroll
                for (int m = 0; m < 8; ++m) a[m] = fz;
                #pragma unroll
                for (int k = 0; k < 4; ++k)        // 8 independent accumulators per k step
                    #pragma unroll
                    for (int m = 0; m < 8; ++m)
                        a[m] = __builtin_amdgcn_mfma_f32_16x16x32_f16(af[m][k], bfr[k], a[m], 0, 0, 0);

                float cm = -3.4e38f;
                #pragma unroll
                for (int m = 0; m < 8; ++m)
                    #pragma unroll
                    for (int r = 0; r < 4; ++r)
                        cm = fmaxf(cm, a[m][r]);
                cm = fmaxf(cm, __shfl_xor(cm, 16, 64));
                cm = fmaxf(cm, __shfl_xor(cm, 32, 64));
                if (quad == 0)
                    out[bid * 256 + wn0 + nn * 16 + l15] = cm;
            }
        }
        __syncthreads();   // protect s_seq/s_trsf before next rep's phase 0
    }
}

extern "C" void kernel_launch(void* const* d_in, const int* in_sizes, int n_in,
                              void* d_out, int out_size, void* d_ws, size_t ws_size,
                              hipStream_t stream) {
    const float* hidden = (const float*)d_in[0];
    const float* mask   = (const float*)d_in[1];
    const float* w      = (const float*)d_in[2];
    const float* bias   = (const float*)d_in[3];
    float* out = (float*)d_out;

    const size_t lds_bytes = (size_t)(2 * 128 * LSTR) * sizeof(_Float16); // 135168 B
    hipFuncSetAttribute(reinterpret_cast<const void*>(entity_tile_kernel),
                        hipFuncAttributeMaxDynamicSharedMemorySize, (int)lds_bytes);
    hipLaunchKernelGGL(entity_tile_kernel, dim3(256), dim3(512), lds_bytes, stream,
                       hidden, mask, w, bias, out, 4);
}

// Round 5
// 607.315 us; speedup vs baseline: 1.1260x; 1.1260x over previous
//
#include <hip/hip_runtime.h>

typedef __attribute__((ext_vector_type(8))) _Float16 f16x8;
typedef __attribute__((ext_vector_type(4))) _Float16 f16x4;
typedef __attribute__((ext_vector_type(4))) float f32x4;

#define LSTR 264   // halves; 528 B row stride, 16B-aligned for ds_read_b128
#define SS 4096
#define SD 256
#define SEG 128

__device__ __forceinline__ float fast_tanh(float x) {
    x = fminf(fmaxf(x, -15.f), 15.f);
    float ex = __expf(2.f * x);
    return (ex - 1.f) / (ex + 1.f);
}

// One block per (b,e) tile; 512 threads = 8 waves = 2 waves/SIMD.
// f32 I/O, fp16 MFMA compute, f32 accumulate. LDS 132 KB -> 1 block/CU.
// R5: all global loads (seq both chunks, w, bias, mask) issued before the first
// barrier; phase 1 pipelined over two 64-row seq chunks so MFMAs on chunk 0
// overlap chunk 1's in-flight loads.
extern "C" __global__ __launch_bounds__(512, 2)
void entity_tile_kernel(const float* __restrict__ hidden,
                        const float* __restrict__ mask,
                        const float* __restrict__ w,
                        const float* __restrict__ bias,
                        float* __restrict__ out)
{
    extern __shared__ _Float16 smem[];
    _Float16* s_trsf = smem;                // 128 x LSTR (reused for attn)
    _Float16* s_seq  = smem + 128 * LSTR;   // 128 x LSTR

    const int bid  = blockIdx.x;            // b*32 + e
    const int b    = bid >> 5;
    const int e    = bid & 31;
    const int tid  = threadIdx.x;
    const int wv   = tid >> 6;               // 0..7
    const int lane = tid & 63;
    const int quad = lane >> 4;
    const int l15  = lane & 15;
    const int wn0  = wv * 32;

    // ---------- pre-barrier: issue ALL global loads ----------
    const float4* g4 = (const float4*)(hidden + (size_t)bid * (SEG * SD));
    float4 c0[8], c1[8];
    #pragma unroll
    for (int i = 0; i < 8; ++i) c0[i] = g4[i * 512 + tid];           // rows 0..63
    #pragma unroll
    for (int i = 0; i < 8; ++i) c1[i] = g4[(i + 8) * 512 + tid];     // rows 64..127

    // w: rows wn0+nn*16+l15, cols k*32+quad*8..+8  -> f16 fragments (grouped cvt
    // keeps transient float4 pressure at ~8 regs/lane-group)
    f16x8 wb[2][8];
    float bv[2];
    #pragma unroll
    for (int nn = 0; nn < 2; ++nn) {
        const float* wrow = w + (size_t)(wn0 + nn * 16 + l15) * SD;
        #pragma unroll
        for (int kg = 0; kg < 2; ++kg) {          // groups of 4 k-blocks
            float4 u[8];
            #pragma unroll
            for (int k = 0; k < 4; ++k) {
                const float4* p = (const float4*)(wrow + (kg * 4 + k) * 32 + quad * 8);
                u[2 * k]     = p[0];
                u[2 * k + 1] = p[1];
            }
            #pragma unroll
            for (int k = 0; k < 4; ++k) {
                float4 u0 = u[2 * k], u1 = u[2 * k + 1];
                f16x8 v = { (_Float16)u0.x, (_Float16)u0.y, (_Float16)u0.z, (_Float16)u0.w,
                            (_Float16)u1.x, (_Float16)u1.y, (_Float16)u1.z, (_Float16)u1.w };
                wb[nn][kg * 4 + k] = v;
            }
        }
        bv[nn] = bias[wn0 + nn * 16 + l15];
    }

    // diagonal mask block, C-layout for score rows [wv*16,+16)
    float mraw[8][4];
    {
        const int lw = wv * 16;
        const size_t mbase = (((size_t)b * SS) + (size_t)e * SEG) * SS + (size_t)e * SEG;
        #pragma unroll
        for (int r = 0; r < 4; ++r) {
            const int l = lw + quad * 4 + r;
            #pragma unroll
            for (int n = 0; n < 8; ++n)
                mraw[n][r] = mask[mbase + (size_t)l * SS + n * 16 + l15];
        }
    }

    // new_mask (input-independent), fire-and-forget stores
    {
        float* nm = out + 65536 + (size_t)bid * 4096;
        #pragma unroll
        for (int i = 0; i < 2; ++i) {
            int idx = i * 512 + tid;
            float val = ((idx >> 5) == e) ? 1.0f : 0.0f;
            float4 q = {val, val, val, val};
            *(float4*)&nm[idx << 2] = q;
        }
    }

    // commit chunk 0 to LDS (waits only c0 — oldest loads)
    #pragma unroll
    for (int i = 0; i < 8; ++i) {
        int idx  = i * 512 + tid;
        int row  = idx >> 6;
        int col4 = (idx & 63) << 2;
        float4 v = c0[i];
        f16x4 h = { (_Float16)v.x, (_Float16)v.y, (_Float16)v.z, (_Float16)v.w };
        *(f16x4*)&s_seq[row * LSTR + col4] = h;
    }
    __syncthreads();   // chunk 0 visible; c1/w/mask may still be in flight

    const f32x4 fz = {0.f, 0.f, 0.f, 0.f};

    // ---------- phase 1a: trsf rows 0..63 (chunk 0), overlapping chunk-1 loads ----------
    #pragma unroll
    for (int m2 = 0; m2 < 2; ++m2) {
        f32x4 acc[2][2] = {{fz, fz}, {fz, fz}};
        #pragma unroll
        for (int k = 0; k < 8; ++k) {
            f16x8 a0 = *(const f16x8*)&s_seq[(m2 * 32 +      l15) * LSTR + k * 32 + quad * 8];
            f16x8 a1 = *(const f16x8*)&s_seq[(m2 * 32 + 16 + l15) * LSTR + k * 32 + quad * 8];
            #pragma unroll
            for (int nn = 0; nn < 2; ++nn) {
                acc[0][nn] = __builtin_amdgcn_mfma_f32_16x16x32_f16(a0, wb[nn][k], acc[0][nn], 0, 0, 0);
                acc[1][nn] = __builtin_amdgcn_mfma_f32_16x16x32_f16(a1, wb[nn][k], acc[1][nn], 0, 0, 0);
            }
        }
        #pragma unroll
        for (int h = 0; h < 2; ++h)
            #pragma unroll
            for (int nn = 0; nn < 2; ++nn)
                #pragma unroll
                for (int r = 0; r < 4; ++r)
                    s_trsf[(m2 * 32 + h * 16 + quad * 4 + r) * LSTR + wn0 + nn * 16 + l15] =
                        (_Float16)fast_tanh(acc[h][nn][r] + bv[nn]);
    }

    // commit chunk 1 to LDS (loads should be long done by now)
    #pragma unroll
    for (int i = 0; i < 8; ++i) {
        int idx  = (i + 8) * 512 + tid;
        int row  = idx >> 6;
        int col4 = (idx & 63) << 2;
        float4 v = c1[i];
        f16x4 h = { (_Float16)v.x, (_Float16)v.y, (_Float16)v.z, (_Float16)v.w };
        *(f16x4*)&s_seq[row * LSTR + col4] = h;
    }
    __syncthreads();   // chunk 1 visible

    // ---------- phase 1b: trsf rows 64..127 (chunk 1) ----------
    #pragma unroll
    for (int m2 = 2; m2 < 4; ++m2) {
        f32x4 acc[2][2] = {{fz, fz}, {fz, fz}};
        #pragma unroll
        for (int k = 0; k < 8; ++k) {
            f16x8 a0 = *(const f16x8*)&s_seq[(m2 * 32 +      l15) * LSTR + k * 32 + quad * 8];
            f16x8 a1 = *(const f16x8*)&s_seq[(m2 * 32 + 16 + l15) * LSTR + k * 32 + quad * 8];
            #pragma unroll
            for (int nn = 0; nn < 2; ++nn) {
                acc[0][nn] = __builtin_amdgcn_mfma_f32_16x16x32_f16(a0, wb[nn][k], acc[0][nn], 0, 0, 0);
                acc[1][nn] = __builtin_amdgcn_mfma_f32_16x16x32_f16(a1, wb[nn][k], acc[1][nn], 0, 0, 0);
            }
        }
        #pragma unroll
        for (int h = 0; h < 2; ++h)
            #pragma unroll
            for (int nn = 0; nn < 2; ++nn)
                #pragma unroll
                for (int r = 0; r < 4; ++r)
                    s_trsf[(m2 * 32 + h * 16 + quad * 4 + r) * LSTR + wn0 + nn * 16 + l15] =
                        (_Float16)fast_tanh(acc[h][nn][r] + bv[nn]);
    }
    __syncthreads();   // trsf fully visible

    // ---------- phase 2: scores rows [wv*16,+16) = trsf @ seq^T; softmax; attn -> s_trsf ----------
    {
        const int lw = wv * 16;
        f16x8 at[8];
        #pragma unroll
        for (int k = 0; k < 8; ++k)
            at[k] = *(const f16x8*)&s_trsf[(lw + l15) * LSTR + k * 32 + quad * 8];

        f32x4 sacc[8];
        #pragma unroll
        for (int n = 0; n < 8; ++n) sacc[n] = fz;

        #pragma unroll
        for (int k = 0; k < 8; ++k) {          // 8 independent accumulators per k step
            #pragma unroll
            for (int n = 0; n < 8; ++n) {
                f16x8 bb = *(const f16x8*)&s_seq[(n * 16 + l15) * LSTR + k * 32 + quad * 8];
                sacc[n] = __builtin_amdgcn_mfma_f32_16x16x32_f16(at[k], bb, sacc[n], 0, 0, 0);
            }
        }

        #pragma unroll
        for (int r = 0; r < 4; ++r) {
            const int l = lw + quad * 4 + r;
            float mx = -3.4e38f;
            #pragma unroll
            for (int n = 0; n < 8; ++n) {
                float sv = sacc[n][r] + mraw[n][r];
                sacc[n][r] = sv;
                mx = fmaxf(mx, sv);
            }
            mx = fmaxf(mx, __shfl_xor(mx, 1, 64));
            mx = fmaxf(mx, __shfl_xor(mx, 2, 64));
            mx = fmaxf(mx, __shfl_xor(mx, 4, 64));
            mx = fmaxf(mx, __shfl_xor(mx, 8, 64));
            float sum = 0.f;
            #pragma unroll
            for (int n = 0; n < 8; ++n) {
                float ev = __expf(sacc[n][r] - mx);
                sacc[n][r] = ev;
                sum += ev;
            }
            sum += __shfl_xor(sum, 1, 64);
            sum += __shfl_xor(sum, 2, 64);
            sum += __shfl_xor(sum, 4, 64);
            sum += __shfl_xor(sum, 8, 64);
            float inv = 1.f / sum;
            #pragma unroll
            for (int n = 0; n < 8; ++n)
                s_trsf[(size_t)l * LSTR + n * 16 + l15] = (_Float16)(sacc[n][r] * inv);
        }
    }
    __syncthreads();

    // ---------- phase 3: ctx = attn @ seq; pooled = colmax; wave owns d-cols [wv*32,+32) ----------
    {
        f16x8 af[8][4];
        #pragma unroll
        for (int m = 0; m < 8; ++m)
            #pragma unroll
            for (int k = 0; k < 4; ++k)
                af[m][k] = *(const f16x8*)&s_trsf[(m * 16 + l15) * LSTR + k * 32 + quad * 8];

        #pragma unroll
        for (int nn = 0; nn < 2; ++nn) {
            f16x8 bfr[4];
            #pragma unroll
            for (int k = 0; k < 4; ++k) {
                f16x8 t;
                #pragma unroll
                for (int j = 0; j < 8; ++j)
                    t[j] = s_seq[(k * 32 + quad * 8 + j) * LSTR + wn0 + nn * 16 + l15];
                bfr[k] = t;
            }
            f32x4 a[8];
            #pragma unroll
            for (int m = 0; m < 8; ++m) a[m] = fz;
            #pragma unroll
            for (int k = 0; k < 4; ++k)        // 8 independent accumulators per k step
                #pragma unroll
                for (int m = 0; m < 8; ++m)
                    a[m] = __builtin_amdgcn_mfma_f32_16x16x32_f16(af[m][k], bfr[k], a[m], 0, 0, 0);

            float cm = -3.4e38f;
            #pragma unroll
            for (int m = 0; m < 8; ++m)
                #pragma unroll
                for (int r = 0; r < 4; ++r)
                    cm = fmaxf(cm, a[m][r]);
            cm = fmaxf(cm, __shfl_xor(cm, 16, 64));
            cm = fmaxf(cm, __shfl_xor(cm, 32, 64));
            if (quad == 0)
                out[bid * 256 + wn0 + nn * 16 + l15] = cm;
        }
    }
}

extern "C" void kernel_launch(void* const* d_in, const int* in_sizes, int n_in,
                              void* d_out, int out_size, void* d_ws, size_t ws_size,
                              hipStream_t stream) {
    const float* hidden = (const float*)d_in[0];
    const float* mask   = (const float*)d_in[1];
    const float* w      = (const float*)d_in[2];
    const float* bias   = (const float*)d_in[3];
    float* out = (float*)d_out;

    const size_t lds_bytes = (size_t)(2 * 128 * LSTR) * sizeof(_Float16); // 135168 B
    hipFuncSetAttribute(reinterpret_cast<const void*>(entity_tile_kernel),
                        hipFuncAttributeMaxDynamicSharedMemorySize, (int)lds_bytes);
    hipLaunchKernelGGL(entity_tile_kernel, dim3(256), dim3(512), lds_bytes, stream,
                       hidden, mask, w, bias, out);
}